// Round 13
// baseline (230.105 us; speedup 1.0000x reference)
//
#include <hip/hip_runtime.h>
#include <stdint.h>
#include <stddef.h>

#define DEV __device__ __forceinline__

typedef _Float16 f16x8 __attribute__((ext_vector_type(8)));
typedef float    f32x4 __attribute__((ext_vector_type(4)));
typedef int      i32x4 __attribute__((ext_vector_type(4)));

#define K2E 1.44269504088896340736f
#define SC25 (25.0f * K2E)

DEV uint16_t f2h(float f) {
  _Float16 h = (_Float16)f;
  return __builtin_bit_cast(uint16_t, h);
}
DEV float h2f(uint16_t u) {
  return (float)__builtin_bit_cast(_Float16, u);
}
DEV f16x8 ldfrag(const uint16_t* p) {
  i32x4 v = *(const i32x4*)p;
  return __builtin_bit_cast(f16x8, v);
}
DEV f32x4 mfma16(f16x8 a, f16x8 b, f32x4 c) {
  return __builtin_amdgcn_mfma_f32_16x16x32_f16(a, b, c, 0, 0, 0);
}
// async global->LDS: each lane copies 16B; LDS dest = base + lane*16
DEV void gld_lds16(const uint16_t* g, uint16_t* l) {
  __builtin_amdgcn_global_load_lds(
      (__attribute__((address_space(1))) void*)g,
      (__attribute__((address_space(3))) void*)l, 16, 0, 0);
}

union U16x8 { uint16_t u[8]; i32x4 v; };
union U16x4 { uint16_t u[4]; uint2 v; };

// ---------------- fused prep: casts + weight transposes ---------------------
__global__ __launch_bounds__(256) void prep_kernel(
    const float* __restrict__ x_cls, const float* __restrict__ x_reg,
    const float* __restrict__ W_cls, const float* __restrict__ W_reg,
    uint16_t* __restrict__ xc_b, uint16_t* __restrict__ xr_b,
    uint16_t* __restrict__ Wtc, uint16_t* __restrict__ Wtr) {
  __shared__ float tile[64][65];
  int b = blockIdx.x, tid = threadIdx.x;
  if (b < 2048) {
    const float* in = (b < 1024) ? x_cls : x_reg;
    uint16_t* outp = (b < 1024) ? xc_b : xr_b;
    int i = (b & 1023) * 256 + tid;
    float4 a = *(const float4*)(in + (size_t)i * 8);
    float4 c = *(const float4*)(in + (size_t)i * 8 + 4);
    U16x8 r;
    r.u[0] = f2h(a.x); r.u[1] = f2h(a.y); r.u[2] = f2h(a.z); r.u[3] = f2h(a.w);
    r.u[4] = f2h(c.x); r.u[5] = f2h(c.y); r.u[6] = f2h(c.z); r.u[7] = f2h(c.w);
    *(i32x4*)(outp + (size_t)i * 8) = r.v;
    return;
  }
  const float* W;
  uint16_t* Wt;
  int idx;
  if (b < 2816) { W = W_cls; Wt = Wtc; idx = b - 2048; }
  else          { W = W_reg; Wt = Wtr; idx = b - 2816; }
  int k0 = (idx & 15) * 64;
  int n0 = (idx >> 4) * 64;
#pragma unroll
  for (int i = 0; i < 16; ++i) {
    int flat = i * 256 + tid;
    int r = flat >> 6, c = flat & 63;
    tile[r][c] = W[(size_t)(k0 + r) * 3072 + n0 + c];
  }
  __syncthreads();
#pragma unroll
  for (int i = 0; i < 16; ++i) {
    int flat = i * 256 + tid;
    int r = flat >> 6, c = flat & 63;
    Wt[(size_t)(n0 + r) * 1024 + k0 + c] = f2h(tile[c][r]);
  }
}

// ---------------- fused QKV GEMM + l2norm + pack ----------------------------
__global__ __launch_bounds__(256, 3) void gemm_qkv_norm_kernel(
    const uint16_t* __restrict__ xc, const uint16_t* __restrict__ Wtc,
    const uint16_t* __restrict__ xr, const uint16_t* __restrict__ Wtr,
    uint16_t* __restrict__ Qc, uint16_t* __restrict__ Kc,
    uint16_t* __restrict__ Qr, uint16_t* __restrict__ Kr,
    uint16_t* __restrict__ Vt, uint16_t* __restrict__ Vcat,
    float* __restrict__ out) {
  __shared__ __align__(16) uint16_t pool[128 * 136];  // 34816 B
  __shared__ float rowss[2][128];
  uint16_t* As = pool;
  uint16_t* Bs = pool + 8192;

  int bm = blockIdx.x, bn = blockIdx.y;
  int n0 = bm * 128;
  const uint16_t* A;
  const uint16_t* Brow;
  int tz, h, iscls;
  if (bn < 24) {
    A = xc; Brow = Wtc + (size_t)(bn * 128) * 1024;
    tz = bn >> 3; h = bn & 7; iscls = 1;
  } else {
    int b2 = bn - 24;
    A = xr; Brow = Wtr + (size_t)(b2 * 128) * 1024;
    tz = b2 >> 3; h = b2 & 7; iscls = 0;
  }
  int tid = threadIdx.x;
  int w = tid >> 6, lane = tid & 63, quad = lane >> 4, l15 = lane & 15;
  int wm = (w >> 1) * 64, wn = (w & 1) * 64;
  const uint16_t* Arow = A + (size_t)n0 * 1024;
  f32x4 acc[4][4];
  f32x4 zero = {0.f, 0.f, 0.f, 0.f};
#pragma unroll
  for (int i = 0; i < 4; ++i)
#pragma unroll
    for (int j = 0; j < 4; ++j) acc[i][j] = zero;
  int rl = lane >> 3, cl = lane & 7;
  int sw = l15 & 7;
  for (int k0 = 0; k0 < 1024; k0 += 64) {
    __syncthreads();
#pragma unroll
    for (int t = 0; t < 4; ++t) {
      int r0 = w * 32 + t * 8;
      gld_lds16(Arow + (size_t)(r0 + rl) * 1024 + k0 + ((cl ^ rl) << 3), As + r0 * 64);
      gld_lds16(Brow + (size_t)(r0 + rl) * 1024 + k0 + ((cl ^ rl) << 3), Bs + r0 * 64);
    }
    __syncthreads();
#pragma unroll
    for (int ks = 0; ks < 2; ++ks) {
      f16x8 af[4], bf[4];
#pragma unroll
      for (int mt = 0; mt < 4; ++mt)
        af[mt] = ldfrag(As + (wm + mt * 16 + l15) * 64 + ((((ks << 2) + quad) ^ sw) << 3));
#pragma unroll
      for (int nt = 0; nt < 4; ++nt)
        bf[nt] = ldfrag(Bs + (wn + nt * 16 + l15) * 64 + ((((ks << 2) + quad) ^ sw) << 3));
#pragma unroll
      for (int mt = 0; mt < 4; ++mt)
#pragma unroll
        for (int nt = 0; nt < 4; ++nt)
          acc[mt][nt] = mfma16(af[mt], bf[nt], acc[mt][nt]);
    }
  }
  __syncthreads();  // (a)

  float ss[4][4];
#pragma unroll
  for (int mt = 0; mt < 4; ++mt)
#pragma unroll
    for (int r = 0; r < 4; ++r) {
      float s = 0.f;
#pragma unroll
      for (int nt = 0; nt < 4; ++nt) s += acc[mt][nt][r] * acc[mt][nt][r];
      s += __shfl_xor(s, 1);
      s += __shfl_xor(s, 2);
      s += __shfl_xor(s, 4);
      s += __shfl_xor(s, 8);
      ss[mt][r] = s;
    }
  int half = w & 1;
  if (l15 == 0) {
#pragma unroll
    for (int mt = 0; mt < 4; ++mt)
#pragma unroll
      for (int r = 0; r < 4; ++r)
        rowss[half][wm + mt * 16 + quad * 4 + r] = ss[mt][r];
  }
  __syncthreads();  // (b)
  float rn[4][4];
#pragma unroll
  for (int mt = 0; mt < 4; ++mt)
#pragma unroll
    for (int r = 0; r < 4; ++r) {
      int row = wm + mt * 16 + quad * 4 + r;
      rn[mt][r] = rsqrtf(rowss[0][row] + rowss[1][row]);
    }

  uint16_t* tile = pool;
#pragma unroll
  for (int mt = 0; mt < 4; ++mt)
#pragma unroll
    for (int nt = 0; nt < 4; ++nt)
#pragma unroll
      for (int r = 0; r < 4; ++r) {
        int row = wm + mt * 16 + quad * 4 + r;
        int col = wn + nt * 16 + l15;
        tile[row * 136 + col] = f2h(acc[mt][nt][r] * rn[mt][r]);
      }
  if (tz == 2) {
#pragma unroll
    for (int mt = 0; mt < 4; ++mt)
#pragma unroll
      for (int nt = 0; nt < 4; ++nt)
#pragma unroll
        for (int r = 0; r < 4; ++r) {
          int row = wm + mt * 16 + quad * 4 + r;
          int col = wn + nt * 16 + l15;
          out[(size_t)(n0 + row) * 2048 + 1024 + h * 128 + col] = acc[mt][nt][r];
        }
  }
  __syncthreads();  // (c)

  {
    int trow = tid >> 1, tco = (tid & 1) << 6;
    const uint16_t* src = tile + trow * 136 + tco;
    uint16_t* dst;
    size_t base;
    if (tz == 0) { dst = iscls ? Qc : Qr; base = ((size_t)h * 2048 + n0 + trow) * 128 + tco; }
    else if (tz == 1) { dst = iscls ? Kc : Kr; base = ((size_t)h * 2048 + n0 + trow) * 128 + tco; }
    else { dst = Vcat; base = (size_t)(n0 + trow) * 1024 + h * 128 + tco; }
#pragma unroll
    for (int j = 0; j < 8; ++j)
      *(i32x4*)(dst + base + j * 8) = *(const i32x4*)(src + j * 8);
  }

  if (tz == 2) {
    __syncthreads();  // (d)
#pragma unroll
    for (int mt = 0; mt < 4; ++mt)
#pragma unroll
      for (int nt = 0; nt < 4; ++nt)
#pragma unroll
        for (int r = 0; r < 4; ++r) {
          int row = wm + mt * 16 + quad * 4 + r;
          int col = wn + nt * 16 + l15;
          tile[col * 136 + row] = f2h(acc[mt][nt][r]);
        }
    __syncthreads();  // (e)
    int trow = tid >> 1, tco = (tid & 1) << 6;
    size_t base = ((size_t)h * 128 + trow) * 2048 + n0 + tco;
#pragma unroll
    for (int j = 0; j < 8; ++j)
      *(i32x4*)(Vt + base + j * 8) = *(const i32x4*)(tile + trow * 136 + tco + j * 8);
  }
}

// -------- merged: flash attention (512 blocks) + symmetric mask GEMM --------
// attn is dependency-bound at 58% issue (2 blocks/CU, register-locked);
// gemm_mask is MFMA-dense and independent (disjoint reads/writes). Merged
// into one 768-block launch with interleaved IDs (bx%3==0 -> mask) so mask
// blocks are co-resident and their MFMA work fills attn's idle issue slots.
// Shared 64KB LDS pool; both bodies byte-identical to verified standalones.
__global__ __launch_bounds__(256, 2) void attn_mask_kernel(
    const uint16_t* __restrict__ Qc, const uint16_t* __restrict__ Kc,
    const uint16_t* __restrict__ Qr, const uint16_t* __restrict__ Kr,
    const uint16_t* __restrict__ Vt, const uint16_t* __restrict__ Vcat,
    const float* __restrict__ cls_score, const float* __restrict__ fg_score,
    uint16_t* __restrict__ Opart, float* __restrict__ Mpart,
    float* __restrict__ Lpart, uint8_t* __restrict__ mask) {
  __shared__ __align__(16) uint16_t pool[32768];  // 64 KB

  int bxx = blockIdx.x;
  int tid = threadIdx.x, w = tid >> 6, lane = tid & 63;
  int quad = lane >> 4, l15 = lane & 15;

  if (bxx % 3 == 0) {
    // =================== mask path (256 logical blocks) ===================
    int mb = bxx / 3;
    int bm = mb & 15, bn = mb >> 4;
    if (bm > bn) return;  // symmetry
    uint16_t* As = pool;
    uint16_t* Bs = pool + 8192;
    int wm = (w >> 1) * 64, wn = (w & 1) * 64;
    const uint16_t* Arow = Vcat + (size_t)(bm * 128) * 1024;
    const uint16_t* Brow = Vcat + (size_t)(bn * 128) * 1024;
    f32x4 acc[4][4];
    f32x4 zero = {0.f, 0.f, 0.f, 0.f};
#pragma unroll
    for (int i = 0; i < 4; ++i)
#pragma unroll
      for (int j = 0; j < 4; ++j) acc[i][j] = zero;
    int rl = lane >> 3, cl = lane & 7;
    int sw = l15 & 7;
    for (int k0 = 0; k0 < 1024; k0 += 64) {
      __syncthreads();
#pragma unroll
      for (int t = 0; t < 4; ++t) {
        int r0 = w * 32 + t * 8;
        gld_lds16(Arow + (size_t)(r0 + rl) * 1024 + k0 + ((cl ^ rl) << 3), As + r0 * 64);
        gld_lds16(Brow + (size_t)(r0 + rl) * 1024 + k0 + ((cl ^ rl) << 3), Bs + r0 * 64);
      }
      __syncthreads();
#pragma unroll
      for (int ks = 0; ks < 2; ++ks) {
        f16x8 af[4], bf[4];
#pragma unroll
        for (int mt = 0; mt < 4; ++mt)
          af[mt] = ldfrag(As + (wm + mt * 16 + l15) * 64 + ((((ks << 2) + quad) ^ sw) << 3));
#pragma unroll
        for (int nt = 0; nt < 4; ++nt)
          bf[nt] = ldfrag(Bs + (wn + nt * 16 + l15) * 64 + ((((ks << 2) + quad) ^ sw) << 3));
#pragma unroll
        for (int mt = 0; mt < 4; ++mt)
#pragma unroll
          for (int nt = 0; nt < 4; ++nt)
            acc[mt][nt] = mfma16(af[mt], bf[nt], acc[mt][nt]);
      }
    }
#pragma unroll
    for (int mt = 0; mt < 4; ++mt)
#pragma unroll
      for (int nt = 0; nt < 4; ++nt) {
        int row = bm * 128 + wm + mt * 16 + quad * 4;
        int col = bn * 128 + wn + nt * 16 + l15;
#pragma unroll
        for (int r = 0; r < 4; ++r)
          mask[(size_t)(row + r) * 2048 + col] = (acc[mt][nt][r] > 6.0f) ? 1 : 0;
      }
    if (bm < bn) {
      __syncthreads();
      uint8_t* T = (uint8_t*)As;
#pragma unroll
      for (int mt = 0; mt < 4; ++mt)
#pragma unroll
        for (int nt = 0; nt < 4; ++nt) {
          uint32_t pk = 0;
#pragma unroll
          for (int r = 0; r < 4; ++r)
            pk |= (acc[mt][nt][r] > 6.0f ? 1u : 0u) << (8 * r);
          int c = wn + nt * 16 + l15;
          int r0 = wm + mt * 16 + quad * 4;
          *(uint32_t*)(T + c * 128 + r0) = pk;
        }
      __syncthreads();
      int row = tid >> 1, off = (tid & 1) << 6;
      uint8_t* dst = mask + (size_t)(bn * 128 + row) * 2048 + bm * 128 + off;
#pragma unroll
      for (int j = 0; j < 4; ++j)
        *(i32x4*)(dst + j * 16) = *(const i32x4*)(T + row * 128 + off + j * 16);
    }
    return;
  }

  // ===================== attn path (512 logical blocks) =====================
  int bx = bxx - 1 - bxx / 3;  // bijective onto 0..511
  uint16_t* sK = pool;                 // 16 KB
  uint16_t* sVt = pool + 8192;         // 32 KB (double buffer)
  uint16_t* sP = pool + 8192 + 16384;  // 16 KB

  int h = bx & 7;
  int rest = bx >> 3;
  int s_ = rest & 1;
  int p = (rest >> 1) & 1;
  int q128 = rest >> 2;  // 0..15
  int qb = q128 * 128 + w * 32;
  int mstart = s_ * 1024;
  uint16_t* Pb = sP + w * 2048;

  const uint16_t* Qp = p ? Qr : Qc;
  const float* score = p ? fg_score : cls_score;
  const uint16_t* Kh = (p ? Kr : Kc) + (size_t)h * 2048 * 128;
  const uint16_t* Vh = Vt + (size_t)h * 128 * 2048;

  f16x8 qf[4][2];
#pragma unroll
  for (int hf = 0; hf < 2; ++hf) {
    const uint16_t* qp = Qp + ((size_t)h * 2048 + qb + hf * 16 + l15) * 128;
#pragma unroll
    for (int ks = 0; ks < 4; ++ks) qf[ks][hf] = ldfrag(qp + ks * 32 + quad * 8);
  }

  float sqv[2];
  sqv[0] = score[qb + l15] - 0.1f;
  sqv[1] = score[qb + 16 + l15] - 0.1f;

  float M[2] = {-3.0e38f, -3.0e38f}, Lacc[2] = {0.f, 0.f};
  f32x4 O[2][8];
  f32x4 zero = {0.f, 0.f, 0.f, 0.f};
#pragma unroll
  for (int hf = 0; hf < 2; ++hf)
#pragma unroll
    for (int i = 0; i < 8; ++i) O[hf][i] = zero;

  int krl = lane >> 4, kcl = lane & 15;
  int vrl = lane >> 3, vcl = lane & 7;
  int xk = l15 & 7;

  // prologue: stage K(0) and V(0) into buffer 0, drain at the barrier
  {
    int m0 = mstart;
#pragma unroll
    for (int t = 0; t < 4; ++t) {
      int r0 = w * 16 + t * 4;
      int key = (r0 + krl) & 7;
      gld_lds16(Kh + (size_t)(m0 + r0 + krl) * 128 + ((kcl ^ key) << 3),
                sK + r0 * 128);
    }
#pragma unroll
    for (int t = 0; t < 4; ++t) {
      int d0 = w * 32 + t * 8;
      gld_lds16(Vh + (size_t)(d0 + vrl) * 2048 + m0 + ((vcl ^ vrl) << 3),
                sVt + d0 * 64);
    }
  }
  __syncthreads();

  for (int it = 0; it < 16; ++it) {
    int cur = it & 1;
    int m0 = mstart + it * 64;
    int m1 = m0 + 64;
    const uint16_t* sVtc = sVt + cur * 8192;

    // ---- QK^T: K frag read once, used for both query halves ----
    f32x4 S[2][4];
#pragma unroll
    for (int hf = 0; hf < 2; ++hf)
#pragma unroll
      for (int mt = 0; mt < 4; ++mt) S[hf][mt] = zero;
#pragma unroll
    for (int ks = 0; ks < 4; ++ks)
#pragma unroll
      for (int mt = 0; mt < 4; ++mt) {
        f16x8 kf = ldfrag(sK + (mt * 16 + l15) * 128 + (((ks * 4 + quad) ^ xk) << 3));
        S[0][mt] = mfma16(kf, qf[ks][0], S[0][mt]);
        S[1][mt] = mfma16(kf, qf[ks][1], S[1][mt]);
      }

    __syncthreads();  // (A) all sK reads done; no outstanding vmem here
    if (it < 15) {
#pragma unroll
      for (int t = 0; t < 4; ++t) {
        int r0 = w * 16 + t * 4;
        int key = (r0 + krl) & 7;
        gld_lds16(Kh + (size_t)(m1 + r0 + krl) * 128 + ((kcl ^ key) << 3),
                  sK + r0 * 128);
      }
      uint16_t* sVtn = sVt + (cur ^ 1) * 8192;
#pragma unroll
      for (int t = 0; t < 4; ++t) {
        int d0 = w * 32 + t * 8;
        gld_lds16(Vh + (size_t)(d0 + vrl) * 2048 + m1 + ((vcl ^ vrl) << 3),
                  sVtn + d0 * 64);
      }
    }

    float4 scm4[4];
#pragma unroll
    for (int mt = 0; mt < 4; ++mt)
      scm4[mt] = *(const float4*)(score + m0 + mt * 16 + quad * 4);

    float l2v[2][4][4];
    float vmax[2] = {-3.0e38f, -3.0e38f};
#pragma unroll
    for (int mt = 0; mt < 4; ++mt) {
      float sc[4];
      sc[0] = ((const float*)&scm4[mt])[0];
      sc[1] = ((const float*)&scm4[mt])[1];
      sc[2] = ((const float*)&scm4[mt])[2];
      sc[3] = ((const float*)&scm4[mt])[3];
#pragma unroll
      for (int hf = 0; hf < 2; ++hf)
#pragma unroll
        for (int r = 0; r < 4; ++r) {
          float v = (sc[r] > sqv[hf]) ? S[hf][mt][r] * (sc[r] * SC25) : 0.0f;
          l2v[hf][mt][r] = v;
          vmax[hf] = fmaxf(vmax[hf], v);
        }
    }
    float al[2];
#pragma unroll
    for (int hf = 0; hf < 2; ++hf) {
      float vm = vmax[hf];
      vm = fmaxf(vm, __shfl_xor(vm, 16));
      vm = fmaxf(vm, __shfl_xor(vm, 32));
      float Mnew = fmaxf(M[hf], vm);
      al[hf] = __builtin_amdgcn_exp2f(M[hf] - Mnew);
      M[hf] = Mnew;
      float ssum = 0.f;
#pragma unroll
      for (int mt = 0; mt < 4; ++mt)
#pragma unroll
        for (int r = 0; r < 4; ++r) {
          float pe = __builtin_amdgcn_exp2f(l2v[hf][mt][r] - Mnew);
          l2v[hf][mt][r] = pe;
          ssum += pe;
        }
      Lacc[hf] = Lacc[hf] * al[hf] + ssum;
    }

    unsigned long long anyresc = __ballot(al[0] != 1.0f || al[1] != 1.0f);
    if (anyresc) {
#pragma unroll
      for (int hf = 0; hf < 2; ++hf) {
        float alr[4];
#pragma unroll
        for (int r = 0; r < 4; ++r) alr[r] = __shfl(al[hf], quad * 4 + r);
#pragma unroll
        for (int dt = 0; dt < 8; ++dt)
#pragma unroll
          for (int r = 0; r < 4; ++r) O[hf][dt][r] *= alr[r];
      }
    }

    // ---- packed P-store: 4 f16 per ds_write_b64 (sP is wave-private) ------
#pragma unroll
    for (int hf = 0; hf < 2; ++hf)
#pragma unroll
      for (int mt = 0; mt < 4; ++mt) {
        int blk = mt * 2 + (quad >> 1);
        int addr = (hf * 16 + l15) * 64 + ((blk ^ xk) << 3) + ((quad & 1) << 2);
        U16x4 pk;
        pk.u[0] = f2h(l2v[hf][mt][0]);
        pk.u[1] = f2h(l2v[hf][mt][1]);
        pk.u[2] = f2h(l2v[hf][mt][2]);
        pk.u[3] = f2h(l2v[hf][mt][3]);
        *(uint2*)(Pb + addr) = pk.v;
      }
#pragma unroll
    for (int ks2 = 0; ks2 < 2; ++ks2) {
      f16x8 a0 = ldfrag(Pb + l15 * 64 + (((ks2 * 4 + quad) ^ xk) << 3));
      f16x8 a1 = ldfrag(Pb + (16 + l15) * 64 + (((ks2 * 4 + quad) ^ xk) << 3));
#pragma unroll
      for (int dt = 0; dt < 8; ++dt) {
        f16x8 b = ldfrag(sVtc + (dt * 16 + l15) * 64 + (((ks2 * 4 + quad) ^ xk) << 3));
        O[0][dt] = mfma16(a0, b, O[0][dt]);
        O[1][dt] = mfma16(a1, b, O[1][dt]);
      }
    }

    __syncthreads();  // (B) drains K(it+1) + V(it+1); syncs sK/sVt readers
  }

#pragma unroll
  for (int hf = 0; hf < 2; ++hf) {
    Lacc[hf] += __shfl_xor(Lacc[hf], 16);
    Lacc[hf] += __shfl_xor(Lacc[hf], 32);
  }

  int plane = p * 2 + s_;
  uint16_t* Op = Opart + (size_t)plane * 2097152;
#pragma unroll
  for (int hf = 0; hf < 2; ++hf)
#pragma unroll
    for (int dt = 0; dt < 8; ++dt)
#pragma unroll
      for (int r = 0; r < 4; ++r)
        Op[(size_t)(qb + hf * 16 + quad * 4 + r) * 1024 + h * 128 + dt * 16 + l15] =
            f2h(O[hf][dt][r]);
  if (lane < 16) {
#pragma unroll
    for (int hf = 0; hf < 2; ++hf) {
      int qrow = qb + hf * 16 + lane;
      Mpart[((size_t)plane * 8 + h) * 2048 + qrow] = M[hf];
      Lpart[((size_t)plane * 8 + h) * 2048 + qrow] = Lacc[hf];
    }
  }
}

// ---------------- fused combine + cooperative sim_round2 --------------------
// Phase A: gather masked m-indices (typically 1: the diagonal) into LDS list.
// Phase B: per masked m, all 256 threads compute the 16 (path,head) dots
// cooperatively (thread t: pair=t>>4, dims (t&15)*8..+8). No divergence.
__global__ __launch_bounds__(256) void combine_sim_kernel(
    const uint16_t* __restrict__ Opart, const float* __restrict__ Mpart,
    const float* __restrict__ Lpart, const uint8_t* __restrict__ mask,
    const uint16_t* __restrict__ Qc, const uint16_t* __restrict__ Kc,
    const uint16_t* __restrict__ Qr, const uint16_t* __restrict__ Kr,
    const float* __restrict__ cls_score, const float* __restrict__ fg_score,
    float* __restrict__ out, float* __restrict__ simout) {
  int n = blockIdx.x;
  int t = threadIdx.x;
  __shared__ float sM[2][8], sL[2][8];
  __shared__ float srow[2048];
  __shared__ int mlist[256];
  __shared__ int mcnt;
  __shared__ float pairvals[16];
  __shared__ float psum_s;

  if (t == 0) { mcnt = 0; psum_s = 0.f; }
  if (t < 16) {
    int p = t >> 3, hh = t & 7;
    size_t i1 = ((size_t)(p * 2 + 0) * 8 + hh) * 2048 + n;
    size_t i2 = ((size_t)(p * 2 + 1) * 8 + hh) * 2048 + n;
    float M1 = Mpart[i1], M2 = Mpart[i2];
    float L1 = Lpart[i1], L2 = Lpart[i2];
    float Mx = fmaxf(M1, M2);
    float Lx = L1 * __builtin_amdgcn_exp2f(M1 - Mx) +
               L2 * __builtin_amdgcn_exp2f(M2 - Mx);
    sM[p][hh] = Mx;
    sL[p][hh] = Lx;
  }
#pragma unroll
  for (int i = 0; i < 8; ++i) srow[i * 256 + t] = 0.f;
  __syncthreads();

  // combine partials -> out row n (first 1024 cols)
  {
    int col = t * 4;
    int h = col >> 7;
    float res[4] = {0.f, 0.f, 0.f, 0.f};
#pragma unroll
    for (int p = 0; p < 2; ++p) {
      size_t i1 = ((size_t)(p * 2 + 0) * 8 + h) * 2048 + n;
      size_t i2 = ((size_t)(p * 2 + 1) * 8 + h) * 2048 + n;
      float Mx = sM[p][h];
      float iLx = 0.5f / sL[p][h];
      float f1 = __builtin_amdgcn_exp2f(Mpart[i1] - Mx) * iLx;
      float f2 = __builtin_amdgcn_exp2f(Mpart[i2] - Mx) * iLx;
      const uint16_t* O1 = Opart + (size_t)(p * 2 + 0) * 2097152 + (size_t)n * 1024 + col;
      const uint16_t* O2 = Opart + (size_t)(p * 2 + 1) * 2097152 + (size_t)n * 1024 + col;
      ushort4 a1 = *(const ushort4*)O1;
      ushort4 a2 = *(const ushort4*)O2;
      res[0] += h2f(a1.x) * f1 + h2f(a2.x) * f2;
      res[1] += h2f(a1.y) * f1 + h2f(a2.y) * f2;
      res[2] += h2f(a1.z) * f1 + h2f(a2.z) * f2;
      res[3] += h2f(a1.w) * f1 + h2f(a2.w) * f2;
    }
    float4 r4 = {res[0], res[1], res[2], res[3]};
    *(float4*)(out + (size_t)n * 2048 + col) = r4;
  }

  // Phase A: gather masked indices
  {
    int mbase = t * 8;
    union { unsigned long long v; uint8_t b[8]; } mk;
    mk.v = *(const unsigned long long*)(mask + (size_t)n * 2048 + mbase);
    if (mk.v) {
#pragma unroll
      for (int i = 0; i < 8; ++i)
        if (mk.b[i]) {
          int idx = atomicAdd(&mcnt, 1);
          if (idx < 256) mlist[idx] = mbase + i;
        }
    }
  }
  __syncthreads();
  int cnt = mcnt < 256 ? mcnt : 256;

  // Phase B: cooperative dots per masked m
  int pair = t >> 4;
  int p = pair >> 3, hh = pair & 7;
  int dchunk = (t & 15) * 8;
  const float* sc = p ? fg_score : cls_score;
  float thr = sc[n] - 0.1f;
  f16x8 qv = ldfrag(((p ? Qr : Qc) + ((size_t)hh * 2048 + n) * 128) + dchunk);
  const uint16_t* Kbase = (p ? Kr : Kc) + (size_t)hh * 2048 * 128 + dchunk;
  float iL = 1.0f / sL[p][hh];
  float Mme = sM[p][hh];

  for (int ii = 0; ii < cnt; ++ii) {
    int m = mlist[ii];
    f16x8 kv = ldfrag(Kbase + (size_t)m * 128);
    float d = 0.f;
#pragma unroll
    for (int j = 0; j < 8; ++j) d += (float)qv[j] * (float)kv[j];
    d += __shfl_xor(d, 1);
    d += __shfl_xor(d, 2);
    d += __shfl_xor(d, 4);
    d += __shfl_xor(d, 8);
    if ((t & 15) == 0) {
      float scm = sc[m];
      float logit = (scm > thr) ? d * (scm * SC25) : 0.0f;
      pairvals[pair] = __builtin_amdgcn_exp2f(logit - Mme) * iL;
    }
    __syncthreads();
    if (t == 0) {
      float s = 0.f;
#pragma unroll
      for (int k = 0; k < 16; ++k) s += pairvals[k];
      float val = __builtin_amdgcn_exp2f(s * (K2E / 16.0f));  // e^(s/16)
      srow[m] = val;
      psum_s += val;
    }
    __syncthreads();
  }

  float inv = 1.0f / psum_s;
  int mbase = t * 8;
  float4 r0 = {srow[mbase] * inv, srow[mbase + 1] * inv,
               srow[mbase + 2] * inv, srow[mbase + 3] * inv};
  float4 r1 = {srow[mbase + 4] * inv, srow[mbase + 5] * inv,
               srow[mbase + 6] * inv, srow[mbase + 7] * inv};
  *(float4*)(simout + (size_t)n * 2048 + mbase) = r0;
  *(float4*)(simout + (size_t)n * 2048 + mbase + 4) = r1;
}

// ---------------- host launch ------------------------------------------------
extern "C" void kernel_launch(void* const* d_in, const int* in_sizes, int n_in,
                              void* d_out, int out_size, void* d_ws, size_t ws_size,
                              hipStream_t stream) {
  const float* x_cls = (const float*)d_in[0];
  const float* x_reg = (const float*)d_in[1];
  const float* cls_score = (const float*)d_in[2];
  const float* fg_score = (const float*)d_in[3];
  const float* W_cls = (const float*)d_in[4];
  const float* W_reg = (const float*)d_in[5];
  float* out = (float*)d_out;
  char* ws = (char*)d_ws;

  const size_t OFF_XC   = 0;
  const size_t OFF_XR   = OFF_XC + 4194304;
  const size_t OFF_WTC  = OFF_XR + 4194304;
  const size_t OFF_WTR  = OFF_WTC + 6291456;
  const size_t OFF_QC   = OFF_WTR + 4194304;
  const size_t OFF_KC   = OFF_QC + 4194304;
  const size_t OFF_QR   = OFF_KC + 4194304;
  const size_t OFF_KR   = OFF_QR + 4194304;
  const size_t OFF_VT   = OFF_KR + 4194304;
  const size_t OFF_VCAT = OFF_VT + 4194304;
  const size_t OFF_OP   = OFF_VCAT + 4194304;   // 16 MB
  const size_t OFF_MP   = OFF_OP + 16777216;    // 256 KB
  const size_t OFF_LP   = OFF_MP + 262144;      // 256 KB
  const size_t OFF_MASK = OFF_LP + 262144;      // 4 MB

  uint16_t* xc_b = (uint16_t*)(ws + OFF_XC);
  uint16_t* xr_b = (uint16_t*)(ws + OFF_XR);
  uint16_t* Wtc  = (uint16_t*)(ws + OFF_WTC);
  uint16_t* Wtr  = (uint16_t*)(ws + OFF_WTR);
  uint16_t* Qc   = (uint16_t*)(ws + OFF_QC);
  uint16_t* Kc   = (uint16_t*)(ws + OFF_KC);
  uint16_t* Qr   = (uint16_t*)(ws + OFF_QR);
  uint16_t* Kr   = (uint16_t*)(ws + OFF_KR);
  uint16_t* Vt   = (uint16_t*)(ws + OFF_VT);
  uint16_t* Vcat = (uint16_t*)(ws + OFF_VCAT);
  uint16_t* Opart = (uint16_t*)(ws + OFF_OP);
  float* Mpart   = (float*)(ws + OFF_MP);
  float* Lpart   = (float*)(ws + OFF_LP);
  uint8_t* mask  = (uint8_t*)(ws + OFF_MASK);

  prep_kernel<<<3328, 256, 0, stream>>>(x_cls, x_reg, W_cls, W_reg,
                                        xc_b, xr_b, Wtc, Wtr);
  gemm_qkv_norm_kernel<<<dim3(16, 40), 256, 0, stream>>>(
      xc_b, Wtc, xr_b, Wtr, Qc, Kc, Qr, Kr, Vt, Vcat, out);
  attn_mask_kernel<<<768, 256, 0, stream>>>(Qc, Kc, Qr, Kr, Vt, Vcat,
                                            cls_score, fg_score,
                                            Opart, Mpart, Lpart, mask);
  combine_sim_kernel<<<2048, 256, 0, stream>>>(Opart, Mpart, Lpart, mask,
                                               Qc, Kc, Qr, Kr, cls_score,
                                               fg_score, out, out + 4194304);
}

// Round 14
// 213.786 us; speedup vs baseline: 1.0763x; 1.0763x over previous
//
#include <hip/hip_runtime.h>
#include <stdint.h>
#include <stddef.h>

#define DEV __device__ __forceinline__

typedef _Float16 f16x8 __attribute__((ext_vector_type(8)));
typedef float    f32x4 __attribute__((ext_vector_type(4)));
typedef int      i32x4 __attribute__((ext_vector_type(4)));

#define K2E 1.44269504088896340736f
#define SC25 (25.0f * K2E)

DEV uint16_t f2h(float f) {
  _Float16 h = (_Float16)f;
  return __builtin_bit_cast(uint16_t, h);
}
DEV float h2f(uint16_t u) {
  return (float)__builtin_bit_cast(_Float16, u);
}
DEV f16x8 ldfrag(const uint16_t* p) {
  i32x4 v = *(const i32x4*)p;
  return __builtin_bit_cast(f16x8, v);
}
DEV f32x4 mfma16(f16x8 a, f16x8 b, f32x4 c) {
  return __builtin_amdgcn_mfma_f32_16x16x32_f16(a, b, c, 0, 0, 0);
}
// async global->LDS: each lane copies 16B; LDS dest = base + lane*16
DEV void gld_lds16(const uint16_t* g, uint16_t* l) {
  __builtin_amdgcn_global_load_lds(
      (__attribute__((address_space(1))) void*)g,
      (__attribute__((address_space(3))) void*)l, 16, 0, 0);
}

union U16x8 { uint16_t u[8]; i32x4 v; };
union U16x4 { uint16_t u[4]; uint2 v; };

// ---------------- fused prep: casts + weight transposes ---------------------
__global__ __launch_bounds__(256) void prep_kernel(
    const float* __restrict__ x_cls, const float* __restrict__ x_reg,
    const float* __restrict__ W_cls, const float* __restrict__ W_reg,
    uint16_t* __restrict__ xc_b, uint16_t* __restrict__ xr_b,
    uint16_t* __restrict__ Wtc, uint16_t* __restrict__ Wtr) {
  __shared__ float tile[64][65];
  int b = blockIdx.x, tid = threadIdx.x;
  if (b < 2048) {
    const float* in = (b < 1024) ? x_cls : x_reg;
    uint16_t* outp = (b < 1024) ? xc_b : xr_b;
    int i = (b & 1023) * 256 + tid;
    float4 a = *(const float4*)(in + (size_t)i * 8);
    float4 c = *(const float4*)(in + (size_t)i * 8 + 4);
    U16x8 r;
    r.u[0] = f2h(a.x); r.u[1] = f2h(a.y); r.u[2] = f2h(a.z); r.u[3] = f2h(a.w);
    r.u[4] = f2h(c.x); r.u[5] = f2h(c.y); r.u[6] = f2h(c.z); r.u[7] = f2h(c.w);
    *(i32x4*)(outp + (size_t)i * 8) = r.v;
    return;
  }
  const float* W;
  uint16_t* Wt;
  int idx;
  if (b < 2816) { W = W_cls; Wt = Wtc; idx = b - 2048; }
  else          { W = W_reg; Wt = Wtr; idx = b - 2816; }
  int k0 = (idx & 15) * 64;
  int n0 = (idx >> 4) * 64;
#pragma unroll
  for (int i = 0; i < 16; ++i) {
    int flat = i * 256 + tid;
    int r = flat >> 6, c = flat & 63;
    tile[r][c] = W[(size_t)(k0 + r) * 3072 + n0 + c];
  }
  __syncthreads();
#pragma unroll
  for (int i = 0; i < 16; ++i) {
    int flat = i * 256 + tid;
    int r = flat >> 6, c = flat & 63;
    Wt[(size_t)(n0 + r) * 1024 + k0 + c] = f2h(tile[c][r]);
  }
}

// ---------------- fused QKV GEMM + l2norm + pack ----------------------------
__global__ __launch_bounds__(256, 3) void gemm_qkv_norm_kernel(
    const uint16_t* __restrict__ xc, const uint16_t* __restrict__ Wtc,
    const uint16_t* __restrict__ xr, const uint16_t* __restrict__ Wtr,
    uint16_t* __restrict__ Qc, uint16_t* __restrict__ Kc,
    uint16_t* __restrict__ Qr, uint16_t* __restrict__ Kr,
    uint16_t* __restrict__ Vt, uint16_t* __restrict__ Vcat,
    float* __restrict__ out) {
  __shared__ __align__(16) uint16_t pool[128 * 136];  // 34816 B
  __shared__ float rowss[2][128];
  uint16_t* As = pool;
  uint16_t* Bs = pool + 8192;

  int bm = blockIdx.x, bn = blockIdx.y;
  int n0 = bm * 128;
  const uint16_t* A;
  const uint16_t* Brow;
  int tz, h, iscls;
  if (bn < 24) {
    A = xc; Brow = Wtc + (size_t)(bn * 128) * 1024;
    tz = bn >> 3; h = bn & 7; iscls = 1;
  } else {
    int b2 = bn - 24;
    A = xr; Brow = Wtr + (size_t)(b2 * 128) * 1024;
    tz = b2 >> 3; h = b2 & 7; iscls = 0;
  }
  int tid = threadIdx.x;
  int w = tid >> 6, lane = tid & 63, quad = lane >> 4, l15 = lane & 15;
  int wm = (w >> 1) * 64, wn = (w & 1) * 64;
  const uint16_t* Arow = A + (size_t)n0 * 1024;
  f32x4 acc[4][4];
  f32x4 zero = {0.f, 0.f, 0.f, 0.f};
#pragma unroll
  for (int i = 0; i < 4; ++i)
#pragma unroll
    for (int j = 0; j < 4; ++j) acc[i][j] = zero;
  int rl = lane >> 3, cl = lane & 7;
  int sw = l15 & 7;
  for (int k0 = 0; k0 < 1024; k0 += 64) {
    __syncthreads();
#pragma unroll
    for (int t = 0; t < 4; ++t) {
      int r0 = w * 32 + t * 8;
      gld_lds16(Arow + (size_t)(r0 + rl) * 1024 + k0 + ((cl ^ rl) << 3), As + r0 * 64);
      gld_lds16(Brow + (size_t)(r0 + rl) * 1024 + k0 + ((cl ^ rl) << 3), Bs + r0 * 64);
    }
    __syncthreads();
#pragma unroll
    for (int ks = 0; ks < 2; ++ks) {
      f16x8 af[4], bf[4];
#pragma unroll
      for (int mt = 0; mt < 4; ++mt)
        af[mt] = ldfrag(As + (wm + mt * 16 + l15) * 64 + ((((ks << 2) + quad) ^ sw) << 3));
#pragma unroll
      for (int nt = 0; nt < 4; ++nt)
        bf[nt] = ldfrag(Bs + (wn + nt * 16 + l15) * 64 + ((((ks << 2) + quad) ^ sw) << 3));
#pragma unroll
      for (int mt = 0; mt < 4; ++mt)
#pragma unroll
        for (int nt = 0; nt < 4; ++nt)
          acc[mt][nt] = mfma16(af[mt], bf[nt], acc[mt][nt]);
    }
  }
  __syncthreads();  // (a)

  float ss[4][4];
#pragma unroll
  for (int mt = 0; mt < 4; ++mt)
#pragma unroll
    for (int r = 0; r < 4; ++r) {
      float s = 0.f;
#pragma unroll
      for (int nt = 0; nt < 4; ++nt) s += acc[mt][nt][r] * acc[mt][nt][r];
      s += __shfl_xor(s, 1);
      s += __shfl_xor(s, 2);
      s += __shfl_xor(s, 4);
      s += __shfl_xor(s, 8);
      ss[mt][r] = s;
    }
  int half = w & 1;
  if (l15 == 0) {
#pragma unroll
    for (int mt = 0; mt < 4; ++mt)
#pragma unroll
      for (int r = 0; r < 4; ++r)
        rowss[half][wm + mt * 16 + quad * 4 + r] = ss[mt][r];
  }
  __syncthreads();  // (b)
  float rn[4][4];
#pragma unroll
  for (int mt = 0; mt < 4; ++mt)
#pragma unroll
    for (int r = 0; r < 4; ++r) {
      int row = wm + mt * 16 + quad * 4 + r;
      rn[mt][r] = rsqrtf(rowss[0][row] + rowss[1][row]);
    }

  uint16_t* tile = pool;
#pragma unroll
  for (int mt = 0; mt < 4; ++mt)
#pragma unroll
    for (int nt = 0; nt < 4; ++nt)
#pragma unroll
      for (int r = 0; r < 4; ++r) {
        int row = wm + mt * 16 + quad * 4 + r;
        int col = wn + nt * 16 + l15;
        tile[row * 136 + col] = f2h(acc[mt][nt][r] * rn[mt][r]);
      }
  if (tz == 2) {
#pragma unroll
    for (int mt = 0; mt < 4; ++mt)
#pragma unroll
      for (int nt = 0; nt < 4; ++nt)
#pragma unroll
        for (int r = 0; r < 4; ++r) {
          int row = wm + mt * 16 + quad * 4 + r;
          int col = wn + nt * 16 + l15;
          out[(size_t)(n0 + row) * 2048 + 1024 + h * 128 + col] = acc[mt][nt][r];
        }
  }
  __syncthreads();  // (c)

  {
    int trow = tid >> 1, tco = (tid & 1) << 6;
    const uint16_t* src = tile + trow * 136 + tco;
    uint16_t* dst;
    size_t base;
    if (tz == 0) { dst = iscls ? Qc : Qr; base = ((size_t)h * 2048 + n0 + trow) * 128 + tco; }
    else if (tz == 1) { dst = iscls ? Kc : Kr; base = ((size_t)h * 2048 + n0 + trow) * 128 + tco; }
    else { dst = Vcat; base = (size_t)(n0 + trow) * 1024 + h * 128 + tco; }
#pragma unroll
    for (int j = 0; j < 8; ++j)
      *(i32x4*)(dst + base + j * 8) = *(const i32x4*)(src + j * 8);
  }

  if (tz == 2) {
    __syncthreads();  // (d)
#pragma unroll
    for (int mt = 0; mt < 4; ++mt)
#pragma unroll
      for (int nt = 0; nt < 4; ++nt)
#pragma unroll
        for (int r = 0; r < 4; ++r) {
          int row = wm + mt * 16 + quad * 4 + r;
          int col = wn + nt * 16 + l15;
          tile[col * 136 + row] = f2h(acc[mt][nt][r]);
        }
    __syncthreads();  // (e)
    int trow = tid >> 1, tco = (tid & 1) << 6;
    size_t base = ((size_t)h * 128 + trow) * 2048 + n0 + tco;
#pragma unroll
    for (int j = 0; j < 8; ++j)
      *(i32x4*)(Vt + base + j * 8) = *(const i32x4*)(tile + trow * 136 + tco + j * 8);
  }
}

// ---------------- mask GEMM: (Vcat.Vcat^T > 6) -> u8, SYMMETRIC -------------
// Gram matrix is symmetric: compute only bm <= bn (136 of 256 blocks do
// work; 47% less MFMA). For bm < bn the transposed tile is staged through
// the dead As buffer (128x128 bytes) and written coalesced.
__global__ __launch_bounds__(256, 3) void gemm_mask_kernel(
    const uint16_t* __restrict__ Vcat, uint8_t* __restrict__ mask) {
  __shared__ __align__(16) uint16_t As[128 * 64];
  __shared__ __align__(16) uint16_t Bs[128 * 64];
  int bm = blockIdx.x, bn = blockIdx.y;
  if (bm > bn) return;  // symmetry
  int tid = threadIdx.x;
  int w = tid >> 6, lane = tid & 63, quad = lane >> 4, l15 = lane & 15;
  int wm = (w >> 1) * 64, wn = (w & 1) * 64;
  const uint16_t* Arow = Vcat + (size_t)(bm * 128) * 1024;
  const uint16_t* Brow = Vcat + (size_t)(bn * 128) * 1024;
  f32x4 acc[4][4];
  f32x4 zero = {0.f, 0.f, 0.f, 0.f};
#pragma unroll
  for (int i = 0; i < 4; ++i)
#pragma unroll
    for (int j = 0; j < 4; ++j) acc[i][j] = zero;
  int rl = lane >> 3, cl = lane & 7;
  int sw = l15 & 7;
  for (int k0 = 0; k0 < 1024; k0 += 64) {
    __syncthreads();
#pragma unroll
    for (int t = 0; t < 4; ++t) {
      int r0 = w * 32 + t * 8;
      gld_lds16(Arow + (size_t)(r0 + rl) * 1024 + k0 + ((cl ^ rl) << 3), As + r0 * 64);
      gld_lds16(Brow + (size_t)(r0 + rl) * 1024 + k0 + ((cl ^ rl) << 3), Bs + r0 * 64);
    }
    __syncthreads();
#pragma unroll
    for (int ks = 0; ks < 2; ++ks) {
      f16x8 af[4], bf[4];
#pragma unroll
      for (int mt = 0; mt < 4; ++mt)
        af[mt] = ldfrag(As + (wm + mt * 16 + l15) * 64 + ((((ks << 2) + quad) ^ sw) << 3));
#pragma unroll
      for (int nt = 0; nt < 4; ++nt)
        bf[nt] = ldfrag(Bs + (wn + nt * 16 + l15) * 64 + ((((ks << 2) + quad) ^ sw) << 3));
#pragma unroll
      for (int mt = 0; mt < 4; ++mt)
#pragma unroll
        for (int nt = 0; nt < 4; ++nt)
          acc[mt][nt] = mfma16(af[mt], bf[nt], acc[mt][nt]);
    }
  }
  // normal-orientation write (upper block, or diagonal)
#pragma unroll
  for (int mt = 0; mt < 4; ++mt)
#pragma unroll
    for (int nt = 0; nt < 4; ++nt) {
      int row = bm * 128 + wm + mt * 16 + quad * 4;
      int col = bn * 128 + wn + nt * 16 + l15;
#pragma unroll
      for (int r = 0; r < 4; ++r)
        mask[(size_t)(row + r) * 2048 + col] = (acc[mt][nt][r] > 6.0f) ? 1 : 0;
    }
  if (bm < bn) {
    // transposed write: stage T[c][r] = bit(r,c) via As (128*128 bytes)
    __syncthreads();  // all As/Bs readers done
    uint8_t* T = (uint8_t*)As;
#pragma unroll
    for (int mt = 0; mt < 4; ++mt)
#pragma unroll
      for (int nt = 0; nt < 4; ++nt) {
        uint32_t pk = 0;
#pragma unroll
        for (int r = 0; r < 4; ++r)
          pk |= (acc[mt][nt][r] > 6.0f ? 1u : 0u) << (8 * r);
        int c = wn + nt * 16 + l15;
        int r0 = wm + mt * 16 + quad * 4;  // multiple of 4
        *(uint32_t*)(T + c * 128 + r0) = pk;
      }
    __syncthreads();
    int row = tid >> 1, off = (tid & 1) << 6;
    uint8_t* dst = mask + (size_t)(bn * 128 + row) * 2048 + bm * 128 + off;
#pragma unroll
    for (int j = 0; j < 4; ++j)
      *(i32x4*)(dst + j * 16) = *(const i32x4*)(T + row * 128 + off + j * 16);
  }
}

// ---------------- flash attention: 32 q/wave, sVt double-buffered -----------
// Verified equal-best (R11, 60.3-61.3us). Locked: 2 waves/SIMD is the
// register-imposed ceiling (R9/R10: any +32-reg scheme or reg-cap spills).
// R13 lesson: do NOT co-schedule with the mask GEMM (L2 thrash, -20us).
__global__ __launch_bounds__(256, 2) void attn_kernel(
    const uint16_t* __restrict__ Qc, const uint16_t* __restrict__ Kc,
    const uint16_t* __restrict__ Qr, const uint16_t* __restrict__ Kr,
    const uint16_t* __restrict__ Vt,
    const float* __restrict__ cls_score, const float* __restrict__ fg_score,
    uint16_t* __restrict__ Opart, float* __restrict__ Mpart,
    float* __restrict__ Lpart) {
  __shared__ __align__(16) uint16_t sK[64 * 128];      // 16 KB
  __shared__ __align__(16) uint16_t sVt[2 * 128 * 64]; // 32 KB double-buffer
  __shared__ __align__(16) uint16_t sP[4 * 32 * 64];   // 16 KB

  int bx = blockIdx.x;
  int h = bx & 7;
  int rest = bx >> 3;
  int s_ = rest & 1;
  int p = (rest >> 1) & 1;
  int q128 = rest >> 2;  // 0..15
  int tid = threadIdx.x, w = tid >> 6, lane = tid & 63;
  int quad = lane >> 4, l15 = lane & 15;
  int qb = q128 * 128 + w * 32;
  int mstart = s_ * 1024;
  uint16_t* Pb = sP + w * 2048;

  const uint16_t* Qp = p ? Qr : Qc;
  const float* score = p ? fg_score : cls_score;
  const uint16_t* Kh = (p ? Kr : Kc) + (size_t)h * 2048 * 128;
  const uint16_t* Vh = Vt + (size_t)h * 128 * 2048;

  f16x8 qf[4][2];
#pragma unroll
  for (int hf = 0; hf < 2; ++hf) {
    const uint16_t* qp = Qp + ((size_t)h * 2048 + qb + hf * 16 + l15) * 128;
#pragma unroll
    for (int ks = 0; ks < 4; ++ks) qf[ks][hf] = ldfrag(qp + ks * 32 + quad * 8);
  }

  float sqv[2];
  sqv[0] = score[qb + l15] - 0.1f;
  sqv[1] = score[qb + 16 + l15] - 0.1f;

  float M[2] = {-3.0e38f, -3.0e38f}, Lacc[2] = {0.f, 0.f};
  f32x4 O[2][8];
  f32x4 zero = {0.f, 0.f, 0.f, 0.f};
#pragma unroll
  for (int hf = 0; hf < 2; ++hf)
#pragma unroll
    for (int i = 0; i < 8; ++i) O[hf][i] = zero;

  int krl = lane >> 4, kcl = lane & 15;
  int vrl = lane >> 3, vcl = lane & 7;
  int xk = l15 & 7;

  // prologue: stage K(0) and V(0) into buffer 0, drain at the barrier
  {
    int m0 = mstart;
#pragma unroll
    for (int t = 0; t < 4; ++t) {
      int r0 = w * 16 + t * 4;
      int key = (r0 + krl) & 7;
      gld_lds16(Kh + (size_t)(m0 + r0 + krl) * 128 + ((kcl ^ key) << 3),
                sK + r0 * 128);
    }
#pragma unroll
    for (int t = 0; t < 4; ++t) {
      int d0 = w * 32 + t * 8;
      gld_lds16(Vh + (size_t)(d0 + vrl) * 2048 + m0 + ((vcl ^ vrl) << 3),
                sVt + d0 * 64);
    }
  }
  __syncthreads();

  for (int it = 0; it < 16; ++it) {
    int cur = it & 1;
    int m0 = mstart + it * 64;
    int m1 = m0 + 64;
    const uint16_t* sVtc = sVt + cur * 8192;

    // ---- QK^T: K frag read once, used for both query halves ----
    f32x4 S[2][4];
#pragma unroll
    for (int hf = 0; hf < 2; ++hf)
#pragma unroll
      for (int mt = 0; mt < 4; ++mt) S[hf][mt] = zero;
#pragma unroll
    for (int ks = 0; ks < 4; ++ks)
#pragma unroll
      for (int mt = 0; mt < 4; ++mt) {
        f16x8 kf = ldfrag(sK + (mt * 16 + l15) * 128 + (((ks * 4 + quad) ^ xk) << 3));
        S[0][mt] = mfma16(kf, qf[ks][0], S[0][mt]);
        S[1][mt] = mfma16(kf, qf[ks][1], S[1][mt]);
      }

    __syncthreads();  // (A) all sK reads done; no outstanding vmem here
    // prefetch K(it+1) -> sK and V(it+1) -> other sVt buffer; both covered
    // by softmax + PV before the forced drain at barrier (B)
    if (it < 15) {
#pragma unroll
      for (int t = 0; t < 4; ++t) {
        int r0 = w * 16 + t * 4;
        int key = (r0 + krl) & 7;
        gld_lds16(Kh + (size_t)(m1 + r0 + krl) * 128 + ((kcl ^ key) << 3),
                  sK + r0 * 128);
      }
      uint16_t* sVtn = sVt + (cur ^ 1) * 8192;
#pragma unroll
      for (int t = 0; t < 4; ++t) {
        int d0 = w * 32 + t * 8;
        gld_lds16(Vh + (size_t)(d0 + vrl) * 2048 + m1 + ((vcl ^ vrl) << 3),
                  sVtn + d0 * 64);
      }
    }

    float4 scm4[4];
#pragma unroll
    for (int mt = 0; mt < 4; ++mt)
      scm4[mt] = *(const float4*)(score + m0 + mt * 16 + quad * 4);

    float l2v[2][4][4];
    float vmax[2] = {-3.0e38f, -3.0e38f};
#pragma unroll
    for (int mt = 0; mt < 4; ++mt) {
      float sc[4];
      sc[0] = ((const float*)&scm4[mt])[0];
      sc[1] = ((const float*)&scm4[mt])[1];
      sc[2] = ((const float*)&scm4[mt])[2];
      sc[3] = ((const float*)&scm4[mt])[3];
#pragma unroll
      for (int hf = 0; hf < 2; ++hf)
#pragma unroll
        for (int r = 0; r < 4; ++r) {
          float v = (sc[r] > sqv[hf]) ? S[hf][mt][r] * (sc[r] * SC25) : 0.0f;
          l2v[hf][mt][r] = v;
          vmax[hf] = fmaxf(vmax[hf], v);
        }
    }
    float al[2];
#pragma unroll
    for (int hf = 0; hf < 2; ++hf) {
      float vm = vmax[hf];
      vm = fmaxf(vm, __shfl_xor(vm, 16));
      vm = fmaxf(vm, __shfl_xor(vm, 32));
      float Mnew = fmaxf(M[hf], vm);
      al[hf] = __builtin_amdgcn_exp2f(M[hf] - Mnew);
      M[hf] = Mnew;
      float ssum = 0.f;
#pragma unroll
      for (int mt = 0; mt < 4; ++mt)
#pragma unroll
        for (int r = 0; r < 4; ++r) {
          float pe = __builtin_amdgcn_exp2f(l2v[hf][mt][r] - Mnew);
          l2v[hf][mt][r] = pe;
          ssum += pe;
        }
      Lacc[hf] = Lacc[hf] * al[hf] + ssum;
    }

    unsigned long long anyresc = __ballot(al[0] != 1.0f || al[1] != 1.0f);
    if (anyresc) {
#pragma unroll
      for (int hf = 0; hf < 2; ++hf) {
        float alr[4];
#pragma unroll
        for (int r = 0; r < 4; ++r) alr[r] = __shfl(al[hf], quad * 4 + r);
#pragma unroll
        for (int dt = 0; dt < 8; ++dt)
#pragma unroll
          for (int r = 0; r < 4; ++r) O[hf][dt][r] *= alr[r];
      }
    }

    // ---- packed P-store: 4 f16 per ds_write_b64 (sP is wave-private) ------
#pragma unroll
    for (int hf = 0; hf < 2; ++hf)
#pragma unroll
      for (int mt = 0; mt < 4; ++mt) {
        int blk = mt * 2 + (quad >> 1);
        int addr = (hf * 16 + l15) * 64 + ((blk ^ xk) << 3) + ((quad & 1) << 2);
        U16x4 pk;
        pk.u[0] = f2h(l2v[hf][mt][0]);
        pk.u[1] = f2h(l2v[hf][mt][1]);
        pk.u[2] = f2h(l2v[hf][mt][2]);
        pk.u[3] = f2h(l2v[hf][mt][3]);
        *(uint2*)(Pb + addr) = pk.v;
      }
#pragma unroll
    for (int ks2 = 0; ks2 < 2; ++ks2) {
      f16x8 a0 = ldfrag(Pb + l15 * 64 + (((ks2 * 4 + quad) ^ xk) << 3));
      f16x8 a1 = ldfrag(Pb + (16 + l15) * 64 + (((ks2 * 4 + quad) ^ xk) << 3));
#pragma unroll
      for (int dt = 0; dt < 8; ++dt) {
        f16x8 b = ldfrag(sVtc + (dt * 16 + l15) * 64 + (((ks2 * 4 + quad) ^ xk) << 3));
        O[0][dt] = mfma16(a0, b, O[0][dt]);
        O[1][dt] = mfma16(a1, b, O[1][dt]);
      }
    }

    __syncthreads();  // (B) drains K(it+1) + V(it+1); syncs sK/sVt readers
  }

#pragma unroll
  for (int hf = 0; hf < 2; ++hf) {
    Lacc[hf] += __shfl_xor(Lacc[hf], 16);
    Lacc[hf] += __shfl_xor(Lacc[hf], 32);
  }

  int plane = p * 2 + s_;
  uint16_t* Op = Opart + (size_t)plane * 2097152;
#pragma unroll
  for (int hf = 0; hf < 2; ++hf)
#pragma unroll
    for (int dt = 0; dt < 8; ++dt)
#pragma unroll
      for (int r = 0; r < 4; ++r)
        Op[(size_t)(qb + hf * 16 + quad * 4 + r) * 1024 + h * 128 + dt * 16 + l15] =
            f2h(O[hf][dt][r]);
  if (lane < 16) {
#pragma unroll
    for (int hf = 0; hf < 2; ++hf) {
      int qrow = qb + hf * 16 + lane;
      Mpart[((size_t)plane * 8 + h) * 2048 + qrow] = M[hf];
      Lpart[((size_t)plane * 8 + h) * 2048 + qrow] = Lacc[hf];
    }
  }
}

// ---------------- fused combine + cooperative sim_round2 --------------------
// Phase A: gather masked m-indices (typically 1: the diagonal) into LDS list.
// Phase B: per masked m, all 256 threads compute the 16 (path,head) dots
// cooperatively (thread t: pair=t>>4, dims (t&15)*8..+8). No divergence.
__global__ __launch_bounds__(256) void combine_sim_kernel(
    const uint16_t* __restrict__ Opart, const float* __restrict__ Mpart,
    const float* __restrict__ Lpart, const uint8_t* __restrict__ mask,
    const uint16_t* __restrict__ Qc, const uint16_t* __restrict__ Kc,
    const uint16_t* __restrict__ Qr, const uint16_t* __restrict__ Kr,
    const float* __restrict__ cls_score, const float* __restrict__ fg_score,
    float* __restrict__ out, float* __restrict__ simout) {
  int n = blockIdx.x;
  int t = threadIdx.x;
  __shared__ float sM[2][8], sL[2][8];
  __shared__ float srow[2048];
  __shared__ int mlist[256];
  __shared__ int mcnt;
  __shared__ float pairvals[16];
  __shared__ float psum_s;

  if (t == 0) { mcnt = 0; psum_s = 0.f; }
  if (t < 16) {
    int p = t >> 3, hh = t & 7;
    size_t i1 = ((size_t)(p * 2 + 0) * 8 + hh) * 2048 + n;
    size_t i2 = ((size_t)(p * 2 + 1) * 8 + hh) * 2048 + n;
    float M1 = Mpart[i1], M2 = Mpart[i2];
    float L1 = Lpart[i1], L2 = Lpart[i2];
    float Mx = fmaxf(M1, M2);
    float Lx = L1 * __builtin_amdgcn_exp2f(M1 - Mx) +
               L2 * __builtin_amdgcn_exp2f(M2 - Mx);
    sM[p][hh] = Mx;
    sL[p][hh] = Lx;
  }
#pragma unroll
  for (int i = 0; i < 8; ++i) srow[i * 256 + t] = 0.f;
  __syncthreads();

  // combine partials -> out row n (first 1024 cols)
  {
    int col = t * 4;
    int h = col >> 7;
    float res[4] = {0.f, 0.f, 0.f, 0.f};
#pragma unroll
    for (int p = 0; p < 2; ++p) {
      size_t i1 = ((size_t)(p * 2 + 0) * 8 + h) * 2048 + n;
      size_t i2 = ((size_t)(p * 2 + 1) * 8 + h) * 2048 + n;
      float Mx = sM[p][h];
      float iLx = 0.5f / sL[p][h];
      float f1 = __builtin_amdgcn_exp2f(Mpart[i1] - Mx) * iLx;
      float f2 = __builtin_amdgcn_exp2f(Mpart[i2] - Mx) * iLx;
      const uint16_t* O1 = Opart + (size_t)(p * 2 + 0) * 2097152 + (size_t)n * 1024 + col;
      const uint16_t* O2 = Opart + (size_t)(p * 2 + 1) * 2097152 + (size_t)n * 1024 + col;
      ushort4 a1 = *(const ushort4*)O1;
      ushort4 a2 = *(const ushort4*)O2;
      res[0] += h2f(a1.x) * f1 + h2f(a2.x) * f2;
      res[1] += h2f(a1.y) * f1 + h2f(a2.y) * f2;
      res[2] += h2f(a1.z) * f1 + h2f(a2.z) * f2;
      res[3] += h2f(a1.w) * f1 + h2f(a2.w) * f2;
    }
    float4 r4 = {res[0], res[1], res[2], res[3]};
    *(float4*)(out + (size_t)n * 2048 + col) = r4;
  }

  // Phase A: gather masked indices
  {
    int mbase = t * 8;
    union { unsigned long long v; uint8_t b[8]; } mk;
    mk.v = *(const unsigned long long*)(mask + (size_t)n * 2048 + mbase);
    if (mk.v) {
#pragma unroll
      for (int i = 0; i < 8; ++i)
        if (mk.b[i]) {
          int idx = atomicAdd(&mcnt, 1);
          if (idx < 256) mlist[idx] = mbase + i;
        }
    }
  }
  __syncthreads();
  int cnt = mcnt < 256 ? mcnt : 256;

  // Phase B: cooperative dots per masked m
  int pair = t >> 4;
  int p = pair >> 3, hh = pair & 7;
  int dchunk = (t & 15) * 8;
  const float* sc = p ? fg_score : cls_score;
  float thr = sc[n] - 0.1f;
  f16x8 qv = ldfrag(((p ? Qr : Qc) + ((size_t)hh * 2048 + n) * 128) + dchunk);
  const uint16_t* Kbase = (p ? Kr : Kc) + (size_t)hh * 2048 * 128 + dchunk;
  float iL = 1.0f / sL[p][hh];
  float Mme = sM[p][hh];

  for (int ii = 0; ii < cnt; ++ii) {
    int m = mlist[ii];
    f16x8 kv = ldfrag(Kbase + (size_t)m * 128);
    float d = 0.f;
#pragma unroll
    for (int j = 0; j < 8; ++j) d += (float)qv[j] * (float)kv[j];
    d += __shfl_xor(d, 1);
    d += __shfl_xor(d, 2);
    d += __shfl_xor(d, 4);
    d += __shfl_xor(d, 8);
    if ((t & 15) == 0) {
      float scm = sc[m];
      float logit = (scm > thr) ? d * (scm * SC25) : 0.0f;
      pairvals[pair] = __builtin_amdgcn_exp2f(logit - Mme) * iL;
    }
    __syncthreads();
    if (t == 0) {
      float s = 0.f;
#pragma unroll
      for (int k = 0; k < 16; ++k) s += pairvals[k];
      float val = __builtin_amdgcn_exp2f(s * (K2E / 16.0f));  // e^(s/16)
      srow[m] = val;
      psum_s += val;
    }
    __syncthreads();
  }

  float inv = 1.0f / psum_s;
  int mbase = t * 8;
  float4 r0 = {srow[mbase] * inv, srow[mbase + 1] * inv,
               srow[mbase + 2] * inv, srow[mbase + 3] * inv};
  float4 r1 = {srow[mbase + 4] * inv, srow[mbase + 5] * inv,
               srow[mbase + 6] * inv, srow[mbase + 7] * inv};
  *(float4*)(simout + (size_t)n * 2048 + mbase) = r0;
  *(float4*)(simout + (size_t)n * 2048 + mbase + 4) = r1;
}

// ---------------- host launch ------------------------------------------------
extern "C" void kernel_launch(void* const* d_in, const int* in_sizes, int n_in,
                              void* d_out, int out_size, void* d_ws, size_t ws_size,
                              hipStream_t stream) {
  const float* x_cls = (const float*)d_in[0];
  const float* x_reg = (const float*)d_in[1];
  const float* cls_score = (const float*)d_in[2];
  const float* fg_score = (const float*)d_in[3];
  const float* W_cls = (const float*)d_in[4];
  const float* W_reg = (const float*)d_in[5];
  float* out = (float*)d_out;
  char* ws = (char*)d_ws;

  const size_t OFF_XC   = 0;
  const size_t OFF_XR   = OFF_XC + 4194304;
  const size_t OFF_WTC  = OFF_XR + 4194304;
  const size_t OFF_WTR  = OFF_WTC + 6291456;
  const size_t OFF_QC   = OFF_WTR + 4194304;
  const size_t OFF_KC   = OFF_QC + 4194304;
  const size_t OFF_QR   = OFF_KC + 4194304;
  const size_t OFF_KR   = OFF_QR + 4194304;
  const size_t OFF_VT   = OFF_KR + 4194304;
  const size_t OFF_VCAT = OFF_VT + 4194304;
  const size_t OFF_OP   = OFF_VCAT + 4194304;   // 16 MB
  const size_t OFF_MP   = OFF_OP + 16777216;    // 256 KB
  const size_t OFF_LP   = OFF_MP + 262144;      // 256 KB
  const size_t OFF_MASK = OFF_LP + 262144;      // 4 MB

  uint16_t* xc_b = (uint16_t*)(ws + OFF_XC);
  uint16_t* xr_b = (uint16_t*)(ws + OFF_XR);
  uint16_t* Wtc  = (uint16_t*)(ws + OFF_WTC);
  uint16_t* Wtr  = (uint16_t*)(ws + OFF_WTR);
  uint16_t* Qc   = (uint16_t*)(ws + OFF_QC);
  uint16_t* Kc   = (uint16_t*)(ws + OFF_KC);
  uint16_t* Qr   = (uint16_t*)(ws + OFF_QR);
  uint16_t* Kr   = (uint16_t*)(ws + OFF_KR);
  uint16_t* Vt   = (uint16_t*)(ws + OFF_VT);
  uint16_t* Vcat = (uint16_t*)(ws + OFF_VCAT);
  uint16_t* Opart = (uint16_t*)(ws + OFF_OP);
  float* Mpart   = (float*)(ws + OFF_MP);
  float* Lpart   = (float*)(ws + OFF_LP);
  uint8_t* mask  = (uint8_t*)(ws + OFF_MASK);

  prep_kernel<<<3328, 256, 0, stream>>>(x_cls, x_reg, W_cls, W_reg,
                                        xc_b, xr_b, Wtc, Wtr);
  gemm_qkv_norm_kernel<<<dim3(16, 40), 256, 0, stream>>>(
      xc_b, Wtc, xr_b, Wtr, Qc, Kc, Qr, Kr, Vt, Vcat, out);
  gemm_mask_kernel<<<dim3(16, 16), 256, 0, stream>>>(Vcat, mask);
  attn_kernel<<<512, 256, 0, stream>>>(Qc, Kc, Qr, Kr, Vt, cls_score, fg_score,
                                       Opart, Mpart, Lpart);
  combine_sim_kernel<<<2048, 256, 0, stream>>>(Opart, Mpart, Lpart, mask,
                                               Qc, Kc, Qr, Kr, cls_score,
                                               fg_score, out, out + 4194304);
}